// Round 2
// baseline (2130.347 us; speedup 1.0000x reference)
//
#include <hip/hip_runtime.h>
#include <math.h>

#define T_ 12
#define N_ 2048
#define D_ 128
#define ND_ 262144            // N_*D_ = 2^18
#define TND_ 3145728L         // T_*ND_

typedef __attribute__((ext_vector_type(8))) short short8;   // 8 bf16 (4 VGPRs)
typedef __attribute__((ext_vector_type(4))) float f32x4;
typedef __attribute__((ext_vector_type(4))) unsigned int u32x4;

__device__ __forceinline__ ushort f2b(float f) {            // fp32 -> bf16 RNE
  unsigned u = __float_as_uint(f);
  u += 0x7fffu + ((u >> 16) & 1u);
  return (ushort)(u >> 16);
}
__device__ __forceinline__ float b2f(ushort s) {
  return __uint_as_float(((unsigned)s) << 16);
}
__device__ __forceinline__ float gelu_f(float v) {
  return 0.5f * v * (1.0f + erff(v * 0.7071067811865475f));
}

typedef union { short8 s8; u32x4 u; } frag_u;

// Direct global->LDS DMA, 16B per lane. LDS dest is wave-uniform base;
// HW writes lane l's 16B at base + l*16 (m97/m104). Matches our fragment
// layout As + blk*512 + l*8 (ushort) exactly.
__device__ __forceinline__ void gload16(const ushort* g, ushort* lds) {
  __builtin_amdgcn_global_load_lds(
      (const __attribute__((address_space(1))) void*)g,
      (__attribute__((address_space(3))) void*)lds, 16, 0, 0);
}

// cos/sin(2*pi*k/12); cos(2*pi*f*t/12) == COS12[(f*t)%12]
__constant__ float COS12[12] = {
    1.0f, 0.8660254037844387f, 0.5f, 0.0f, -0.5f, -0.8660254037844387f,
    -1.0f, -0.8660254037844387f, -0.5f, 0.0f, 0.5f, 0.8660254037844387f};
__constant__ float SIN12[12] = {
    0.0f, 0.5f, 0.8660254037844387f, 1.0f, 0.8660254037844387f, 0.5f,
    0.0f, -0.5f, -0.8660254037844387f, -1.0f, -0.8660254037844387f, -0.5f};

// ---------------------------------------------------------------------------
// bf16 MFMA GEMM: C[M,N] = ACT( alpha * A@B^T + bias ), A bf16 [M,K] (lda),
// B bf16 [N,K] (ldb, torch Linear weight layout). Tile 128x128, BK=32,
// 4 waves, each wave 32(M)x128(N) = 2x8 MFMAs of 16x16x32.
// LDS tiles in MFMA-fragment order via global_load_lds (wave-uniform base +
// lane*16B): block ri holds rows ri*16+(l&15), k (l>>4)*8..+7 at
// offset ri*512 + l*8. Lane-contiguous 16B => conflict-free (m136).
// ACT: 0 none, 1 relu, 2 gelu(exact). OUT: 0 f32, 1 bf16, 2 bf16 transposed
// (C^T, for vT). off0/off1: epilogue col remap c += (c<128 ? off0 : off1).
// Requires M%128==0, N%128==0, K%32==0.
// ---------------------------------------------------------------------------
template <int ACT, int OUT>
__global__ __launch_bounds__(256) void mgemm(
    const ushort* __restrict__ A, const ushort* __restrict__ B,
    const float* __restrict__ bias, void* __restrict__ Cv,
    int K, int lda, int ldb, int ldc, float alpha,
    long sAb, long sBb, long sCb, int off0, int off1) {
  __shared__ ushort As[4096];
  __shared__ ushort Bs[4096];
  const int tid = threadIdx.x;
  const int w = tid >> 6;
  const int l = tid & 63;
  const int lr = l & 15;        // fragment row/col within 16
  const int lg = l >> 4;        // k-group (0..3)
  const int row0 = blockIdx.y * 128;
  const int col0 = blockIdx.x * 128;
  const ushort* Ap = A + sAb * blockIdx.z;
  const ushort* Bp = B + sBb * blockIdx.z;

  f32x4 acc[2][8];
#pragma unroll
  for (int i = 0; i < 2; ++i)
#pragma unroll
    for (int j = 0; j < 8; ++j) acc[i][j] = (f32x4){0.f, 0.f, 0.f, 0.f};

  const int ba = w, bb2 = w + 4;   // each wave stages 2 A-blocks + 2 B-blocks
  const ushort* Apl = Ap + (long)(row0 + ba * 16 + lr) * lda + lg * 8;
  const ushort* Apl2 = Ap + (long)(row0 + bb2 * 16 + lr) * lda + lg * 8;
  const ushort* Bpl = Bp + (long)(col0 + ba * 16 + lr) * ldb + lg * 8;
  const ushort* Bpl2 = Bp + (long)(col0 + bb2 * 16 + lr) * ldb + lg * 8;
  for (int k0 = 0; k0 < K; k0 += 32) {
    gload16(Apl + k0, As + ba * 512);
    gload16(Apl2 + k0, As + bb2 * 512);
    gload16(Bpl + k0, Bs + ba * 512);
    gload16(Bpl2 + k0, Bs + bb2 * 512);
    __syncthreads();
    const short8 a0 = *(const short8*)(As + (w * 2 + 0) * 512 + l * 8);
    const short8 a1 = *(const short8*)(As + (w * 2 + 1) * 512 + l * 8);
#pragma unroll
    for (int ni = 0; ni < 8; ++ni) {
      const short8 bfr = *(const short8*)(Bs + ni * 512 + l * 8);
      acc[0][ni] = __builtin_amdgcn_mfma_f32_16x16x32_bf16(a0, bfr, acc[0][ni], 0, 0, 0);
      acc[1][ni] = __builtin_amdgcn_mfma_f32_16x16x32_bf16(a1, bfr, acc[1][ni], 0, 0, 0);
    }
    __syncthreads();
  }

  // epilogue: C/D layout col=l&15, row=(l>>4)*4+reg  [m89/m91]
  const long Cz = sCb * blockIdx.z;
#pragma unroll
  for (int mi = 0; mi < 2; ++mi) {
    const int grow0 = row0 + w * 32 + mi * 16 + lg * 4;
    if (OUT == 2) {
      ushort* C = (ushort*)Cv;
#pragma unroll
      for (int ni = 0; ni < 8; ++ni) {
        const int c = col0 + ni * 16 + lr;
        const float bv = bias ? bias[c] : 0.f;
        ushort4 pk;
        float v0 = acc[mi][ni][0] * alpha + bv;
        float v1 = acc[mi][ni][1] * alpha + bv;
        float v2 = acc[mi][ni][2] * alpha + bv;
        float v3 = acc[mi][ni][3] * alpha + bv;
        if (ACT == 1) { v0 = fmaxf(v0, 0.f); v1 = fmaxf(v1, 0.f); v2 = fmaxf(v2, 0.f); v3 = fmaxf(v3, 0.f); }
        pk.x = f2b(v0); pk.y = f2b(v1); pk.z = f2b(v2); pk.w = f2b(v3);
        *(ushort4*)(C + (long)c * ldc + grow0) = pk;
      }
    } else {
#pragma unroll
      for (int ni = 0; ni < 8; ++ni) {
        const int c = col0 + ni * 16 + lr;
        const float bv = bias ? bias[c] : 0.f;
        const int cm = c + (c < 128 ? off0 : off1);
#pragma unroll
        for (int r = 0; r < 4; ++r) {
          float v = acc[mi][ni][r] * alpha + bv;
          if (ACT == 1) v = fmaxf(v, 0.f);
          if (ACT == 2) v = 0.5f * v * (1.0f + erff(v * 0.7071067811865475f));
          const long off = Cz + (long)(grow0 + r) * ldc + cm;
          if (OUT == 0) ((float*)Cv)[off] = v;
          else ((ushort*)Cv)[off] = f2b(v);
        }
      }
    }
  }
}

// ---------------------------------------------------------------------------
// conv_up GEMM2 fused with bias + residual(x fp32) + LayerNorm -> hn fp32.
// ---------------------------------------------------------------------------
__global__ __launch_bounds__(256) void mgemm_ln(
    const ushort* __restrict__ A, const ushort* __restrict__ B,
    const float* __restrict__ bias, const float* __restrict__ x,
    const float* __restrict__ gamma, const float* __restrict__ beta,
    float* __restrict__ hn) {
  const int K = 1536;
  __shared__ ushort As[4096];
  __shared__ ushort Bs[4096];
  const int tid = threadIdx.x;
  const int w = tid >> 6;
  const int l = tid & 63;
  const int lr = l & 15;
  const int lg = l >> 4;
  const int row0 = blockIdx.y * 128;
  const int t = blockIdx.x;
  const int col0 = t * 128;

  f32x4 acc[2][8];
#pragma unroll
  for (int i = 0; i < 2; ++i)
#pragma unroll
    for (int j = 0; j < 8; ++j) acc[i][j] = (f32x4){0.f, 0.f, 0.f, 0.f};

  const int ba = w, bb2 = w + 4;
  const ushort* Apl = A + (long)(row0 + ba * 16 + lr) * K + lg * 8;
  const ushort* Apl2 = A + (long)(row0 + bb2 * 16 + lr) * K + lg * 8;
  const ushort* Bpl = B + (long)(col0 + ba * 16 + lr) * K + lg * 8;
  const ushort* Bpl2 = B + (long)(col0 + bb2 * 16 + lr) * K + lg * 8;
  for (int k0 = 0; k0 < K; k0 += 32) {
    gload16(Apl + k0, As + ba * 512);
    gload16(Apl2 + k0, As + bb2 * 512);
    gload16(Bpl + k0, Bs + ba * 512);
    gload16(Bpl2 + k0, Bs + bb2 * 512);
    __syncthreads();
    const short8 a0 = *(const short8*)(As + (w * 2 + 0) * 512 + l * 8);
    const short8 a1 = *(const short8*)(As + (w * 2 + 1) * 512 + l * 8);
#pragma unroll
    for (int ni = 0; ni < 8; ++ni) {
      const short8 bfr = *(const short8*)(Bs + ni * 512 + l * 8);
      acc[0][ni] = __builtin_amdgcn_mfma_f32_16x16x32_bf16(a0, bfr, acc[0][ni], 0, 0, 0);
      acc[1][ni] = __builtin_amdgcn_mfma_f32_16x16x32_bf16(a1, bfr, acc[1][ni], 0, 0, 0);
    }
    __syncthreads();
  }

#pragma unroll
  for (int mi = 0; mi < 2; ++mi) {
#pragma unroll
    for (int r = 0; r < 4; ++r) {
      const int gr = row0 + w * 32 + mi * 16 + lg * 4 + r;
      const int bb = gr >> 11;
      const int nn = gr & 2047;
      const long base = ((long)(bb * 12 + t) << 18) + (long)nn * 128;
      float h[8];
      float s1 = 0.f, s2 = 0.f;
#pragma unroll
      for (int ni = 0; ni < 8; ++ni) {
        const int d = ni * 16 + lr;
        const float v = acc[mi][ni][r] + bias[col0 + d] + x[base + d];
        h[ni] = v;
        s1 += v;
        s2 += v * v;
      }
#pragma unroll
      for (int m = 1; m < 16; m <<= 1) {
        s1 += __shfl_xor(s1, m);
        s2 += __shfl_xor(s2, m);
      }
      const float mu = s1 * (1.f / 128.f);
      const float rstd = rsqrtf(s2 * (1.f / 128.f) - mu * mu + 1e-5f);
#pragma unroll
      for (int ni = 0; ni < 8; ++ni) {
        const int d = ni * 16 + lr;
        hn[base + d] = (h[ni] - mu) * rstd * gamma[d] + beta[d];
      }
    }
  }
}

// ---------------------------------------------------------------------------
// Fused FFT-MLP: per 128-row M-tile of re/im [Fr][128]:
//   hr = gelu(re@Wr1^T+br1)@Wr2^T - gelu(im@Wi1^T+bi1)@Wi2^T + (br2-bi2)
//   hi = gelu(re@Wi1^T+bi1)@Wi2^T + gelu(im@Wr1^T+br1)@Wr2^T + (bi2+br2)
// realized as: half h: g_e = gelu(re@W1e+b1e), g_o = gelu(im@W1o+b1o),
//   out_h = [g_e|g_o] @ W2h^T + b2h   (W2h = Whrb / Whib, sign pre-folded).
// Stage 1 SWAPPED (mfma(A=W1,B=src^T)) so each lane's C/D holds one M-row
// (col=l&15) and 32 feature values over (lg,r,ni). After gelu+bf16-pack,
// stage-2 A-fragments are assembled with a fixed lane permutation:
// f=32c+8L+j -> ni=2c+(L>>1), lg_src=2(L&1)+(j>>2), word=(j>>1)&1.
// Weights read as fragments from global (L2-hot, 128KB). No LDS, no barriers.
// ---------------------------------------------------------------------------
__global__ __launch_bounds__(256) void fft_mlp_k(
    const ushort* __restrict__ re, const ushort* __restrict__ im,
    const ushort* __restrict__ Wr1, const ushort* __restrict__ Wi1,
    const float* __restrict__ br1, const float* __restrict__ bi1,
    const ushort* __restrict__ Whr, const ushort* __restrict__ Whi,
    const float* __restrict__ bhr, const float* __restrict__ bhi,
    float* __restrict__ hr, float* __restrict__ hi) {
  const int tid = threadIdx.x;
  const int w = tid >> 6;
  const int l = tid & 63;
  const int lr = l & 15;
  const int lg = l >> 4;
  const long m0 = (long)blockIdx.x * 128 + w * 32;
  const int srcA = lr + ((lg & 1) << 5);   // lane holding lg_src = 2*(L&1)
  const int srcB = srcA + 16;              // lg_src = 2*(L&1)+1
  const bool top = (lg >= 2);              // needs ni = 2c'+1

  for (int h = 0; h < 2; ++h) {
    const ushort* W1e = h ? Wi1 : Wr1;
    const float*  b1e = h ? bi1 : br1;
    const ushort* W1o = h ? Wr1 : Wi1;
    const float*  b1o = h ? br1 : bi1;
    const ushort* W2  = h ? Whi : Whr;
    const float*  b2  = h ? bhi : bhr;
    float* outp = h ? hi : hr;

    unsigned p0[2][8][2], p1[2][8][2];   // packed bf16 g_e / g_o
#pragma unroll
    for (int gi = 0; gi < 2; ++gi) {
      const ushort* Asrc = gi ? im : re;
      const ushort* W1 = gi ? W1o : W1e;
      const float* b1 = gi ? b1o : b1e;
      f32x4 acc[2][8];
#pragma unroll
      for (int i = 0; i < 2; ++i)
#pragma unroll
        for (int j = 0; j < 8; ++j) acc[i][j] = (f32x4){0.f, 0.f, 0.f, 0.f};
#pragma unroll
      for (int kc = 0; kc < 4; ++kc) {
        frag_u bf0, bf1;
        bf0.u = *(const u32x4*)(Asrc + (m0 + lr) * 128 + kc * 32 + lg * 8);
        bf1.u = *(const u32x4*)(Asrc + (m0 + 16 + lr) * 128 + kc * 32 + lg * 8);
#pragma unroll
        for (int ni = 0; ni < 8; ++ni) {
          frag_u af;
          af.u = *(const u32x4*)(W1 + (ni * 16 + lr) * 128 + kc * 32 + lg * 8);
          acc[0][ni] = __builtin_amdgcn_mfma_f32_16x16x32_bf16(af.s8, bf0.s8, acc[0][ni], 0, 0, 0);
          acc[1][ni] = __builtin_amdgcn_mfma_f32_16x16x32_bf16(af.s8, bf1.s8, acc[1][ni], 0, 0, 0);
        }
      }
      // bias + gelu + pack to bf16 pairs (feat = 16ni + 4lg + r)
#pragma unroll
      for (int ni = 0; ni < 8; ++ni) {
        float bb0 = b1[ni * 16 + lg * 4 + 0];
        float bb1 = b1[ni * 16 + lg * 4 + 1];
        float bb2 = b1[ni * 16 + lg * 4 + 2];
        float bb3 = b1[ni * 16 + lg * 4 + 3];
#pragma unroll
        for (int mi = 0; mi < 2; ++mi) {
          float v0 = gelu_f(acc[mi][ni][0] + bb0);
          float v1 = gelu_f(acc[mi][ni][1] + bb1);
          float v2 = gelu_f(acc[mi][ni][2] + bb2);
          float v3 = gelu_f(acc[mi][ni][3] + bb3);
          unsigned w0 = (unsigned)f2b(v0) | ((unsigned)f2b(v1) << 16);
          unsigned w1 = (unsigned)f2b(v2) | ((unsigned)f2b(v3) << 16);
          if (gi == 0) { p0[mi][ni][0] = w0; p0[mi][ni][1] = w1; }
          else         { p1[mi][ni][0] = w0; p1[mi][ni][1] = w1; }
        }
      }
    }

    // stage 2: out = [g_e | g_o] @ W2^T  (K = 256, c = k-chunk of 32)
    f32x4 acc2[2][8];
#pragma unroll
    for (int i = 0; i < 2; ++i)
#pragma unroll
      for (int j = 0; j < 8; ++j) acc2[i][j] = (f32x4){0.f, 0.f, 0.f, 0.f};
#pragma unroll
    for (int c = 0; c < 8; ++c) {
      const int cp = c & 3;
      frag_u A0, A1;
#pragma unroll
      for (int mi = 0; mi < 2; ++mi) {
        unsigned q00, q01, q10, q11;
        if (c < 4) {
          q00 = p0[mi][2 * cp][0];     q01 = p0[mi][2 * cp][1];
          q10 = p0[mi][2 * cp + 1][0]; q11 = p0[mi][2 * cp + 1][1];
        } else {
          q00 = p1[mi][2 * cp][0];     q01 = p1[mi][2 * cp][1];
          q10 = p1[mi][2 * cp + 1][0]; q11 = p1[mi][2 * cp + 1][1];
        }
        unsigned lo0 = (unsigned)__shfl((int)q00, srcA);
        unsigned lo1 = (unsigned)__shfl((int)q01, srcA);
        unsigned lo2 = (unsigned)__shfl((int)q00, srcB);
        unsigned lo3 = (unsigned)__shfl((int)q01, srcB);
        unsigned h0 = (unsigned)__shfl((int)q10, srcA);
        unsigned h1 = (unsigned)__shfl((int)q11, srcA);
        unsigned h2 = (unsigned)__shfl((int)q10, srcB);
        unsigned h3 = (unsigned)__shfl((int)q11, srcB);
        frag_u& A = mi ? A1 : A0;
        A.u[0] = top ? h0 : lo0;
        A.u[1] = top ? h1 : lo1;
        A.u[2] = top ? h2 : lo2;
        A.u[3] = top ? h3 : lo3;
      }
#pragma unroll
      for (int ni = 0; ni < 8; ++ni) {
        frag_u bf;
        bf.u = *(const u32x4*)(W2 + (ni * 16 + lr) * 256 + c * 32 + lg * 8);
        acc2[0][ni] = __builtin_amdgcn_mfma_f32_16x16x32_bf16(A0.s8, bf.s8, acc2[0][ni], 0, 0, 0);
        acc2[1][ni] = __builtin_amdgcn_mfma_f32_16x16x32_bf16(A1.s8, bf.s8, acc2[1][ni], 0, 0, 0);
      }
    }
    // epilogue: row = m0 + 16mi + 4lg + r, col = 16ni + lr
#pragma unroll
    for (int ni = 0; ni < 8; ++ni) {
      const float bb = b2[ni * 16 + lr];
#pragma unroll
      for (int mi = 0; mi < 2; ++mi)
#pragma unroll
        for (int r = 0; r < 4; ++r)
          outp[(m0 + mi * 16 + lg * 4 + r) * 128 + ni * 16 + lr] = acc2[mi][ni][r] + bb;
    }
  }
}

// ---------------------------------------------------------------------------
// Row softmax over 2048 fp32 logits -> bf16 probabilities.
// ---------------------------------------------------------------------------
__global__ __launch_bounds__(256) void softmax_k(const float* __restrict__ S,
                                                 ushort* __restrict__ P) {
  const long row = ((long)blockIdx.y * N_ + blockIdx.x) * N_;
  const float* p = S + row;
  const int tid = threadIdx.x;
  float v[8];
  float mx = -3.4e38f;
#pragma unroll
  for (int j = 0; j < 8; ++j) {
    v[j] = p[tid + 256 * j];
    mx = fmaxf(mx, v[j]);
  }
  __shared__ float red[256];
  red[tid] = mx;
  __syncthreads();
  for (int s = 128; s > 0; s >>= 1) {
    if (tid < s) red[tid] = fmaxf(red[tid], red[tid + s]);
    __syncthreads();
  }
  mx = red[0];
  __syncthreads();
  float sum = 0.0f;
#pragma unroll
  for (int j = 0; j < 8; ++j) {
    v[j] = expf(v[j] - mx);
    sum += v[j];
  }
  red[tid] = sum;
  __syncthreads();
  for (int s = 128; s > 0; s >>= 1) {
    if (tid < s) red[tid] += red[tid + s];
    __syncthreads();
  }
  const float inv = 1.0f / red[0];
#pragma unroll
  for (int j = 0; j < 8; ++j) P[row + tid + 256 * j] = f2b(v[j] * inv);
}

// rfft over T=12: hn fp32 [CB,12,2048,128] -> re/im bf16 [CB,7,2048,128]
__global__ __launch_bounds__(256) void rfft_k(const float* __restrict__ hn,
                                              ushort* __restrict__ re,
                                              ushort* __restrict__ im) {
  const long i = (long)blockIdx.x * 256 + threadIdx.x;
  const int bb = (int)(i >> 18);
  const int nd = (int)(i & (ND_ - 1));
  float ht[12];
#pragma unroll
  for (int t = 0; t < 12; ++t) ht[t] = hn[((long)(bb * T_ + t) << 18) + nd];
#pragma unroll
  for (int f = 0; f < 7; ++f) {
    float sr = 0.0f, si = 0.0f;
#pragma unroll
    for (int t = 0; t < 12; ++t) {
      const int k = (f * t) % 12;
      sr = fmaf(ht[t], COS12[k], sr);
      si = fmaf(ht[t], SIN12[k], si);
    }
    const long off = ((long)(bb * 7 + f) << 18) + nd;
    re[off] = f2b(sr);
    im[off] = f2b(-si);
  }
}

// irfft (n=12, numpy C2R: imag of DC/Nyquist dropped) + residual -> fp32 out
__global__ __launch_bounds__(256) void irfft_k(const float* __restrict__ hr,
                                               const float* __restrict__ hi,
                                               const float* __restrict__ x,
                                               float* __restrict__ out) {
  const long i = (long)blockIdx.x * 256 + threadIdx.x;
  const int bb = (int)(i >> 18);
  const int nd = (int)(i & (ND_ - 1));
  float r[7], m[7];
#pragma unroll
  for (int f = 0; f < 7; ++f) {
    const long off = ((long)(bb * 7 + f) << 18) + nd;
    r[f] = hr[off];
    m[f] = hi[off];
  }
#pragma unroll
  for (int t = 0; t < 12; ++t) {
    float s = r[0] + ((t & 1) ? -r[6] : r[6]);
#pragma unroll
    for (int f = 1; f < 6; ++f) {
      const int k = (f * t) % 12;
      s += 2.0f * (r[f] * COS12[k] - m[f] * SIN12[k]);
    }
    const long xi = ((long)(bb * T_ + t) << 18) + nd;
    out[xi] = s * (1.0f / 12.0f) + x[xi];
  }
}

// x fp32 [CB,12,2048,128] -> xt bf16 [CB*2048, 1536] (transposed conv_down in)
__global__ __launch_bounds__(256) void xt_k(const float* __restrict__ x,
                                            ushort* __restrict__ xt) {
  const long i = (long)blockIdx.x * 256 + threadIdx.x;
  const int d = (int)(i & 127);
  const long r = i >> 7;
  const int nn = (int)(r & 2047);
  const long r2 = r >> 11;
  const int t = (int)(r2 % 12);
  const int bb = (int)(r2 / 12);
  xt[((long)bb * 2048 + nn) * 1536 + t * 128 + d] = f2b(x[i]);
}

// ---------------------------------------------------------------------------
// Weight prep: fp32 -> bf16 with concat/sign-fold fusions + bias combos.
// Weight region (ushort elems):
//   Wd1b@0(196608) Wd2b@196608(16384) Wqkb@212992(32768=[Wq|Wk])
//   Wvb@245760(16384) Wu1b@262144(196608) Wu2b@458752(2359296)
//   W13b@2818048(32768=[Wr1|Wi1]) W24b@2850816(32768=[Wi1|Wr1])
//   Whrb@2883584(32768: [n][k]: k<128?Wr2:-Wi2)  Whib@2916352(32768: Wi2|Wr2)
// Bias region (f32): bqk@0(256) b13@256(256) b24@512(256) bhr@768(128) bhi@896(128)
// ---------------------------------------------------------------------------
__global__ __launch_bounds__(256) void prep_k(
    const float* Wd1, const float* Wd2, const float* Wq, const float* Wk,
    const float* Wv, const float* Wu1, const float* Wu2, const float* Wr1,
    const float* Wr2, const float* Wi1, const float* Wi2,
    const float* bq, const float* bk, const float* br1, const float* bi1,
    const float* br2, const float* bi2,
    ushort* __restrict__ wws, float* __restrict__ bws) {
  const long i = (long)blockIdx.x * 256 + threadIdx.x;
  if (i < 256) bws[i] = (i < 128) ? bq[i] : bk[i - 128];
  else if (i < 512) { const int j = i - 256; bws[i] = (j < 128) ? br1[j] : bi1[j - 128]; }
  else if (i < 768) { const int j = i - 512; bws[i] = (j < 128) ? bi1[j] : br1[j - 128]; }
  else if (i < 896) { const int j = i - 768; bws[i] = br2[j] - bi2[j]; }
  else if (i < 1024) { const int j = i - 896; bws[i] = bi2[j] + br2[j]; }
  if (i >= 2949120) return;
  float v;
  if (i < 196608) v = Wd1[i];
  else if (i < 212992) v = Wd2[i - 196608];
  else if (i < 245760) { const long j = i - 212992; v = (j < 16384) ? Wq[j] : Wk[j - 16384]; }
  else if (i < 262144) v = Wv[i - 245760];
  else if (i < 458752) v = Wu1[i - 262144];
  else if (i < 2818048) v = Wu2[i - 458752];
  else if (i < 2850816) { const long j = i - 2818048; v = (j < 16384) ? Wr1[j] : Wi1[j - 16384]; }
  else if (i < 2883584) { const long j = i - 2850816; v = (j < 16384) ? Wi1[j] : Wr1[j - 16384]; }
  else if (i < 2916352) {
    const long j = i - 2883584; const int n = (int)(j >> 8), k = (int)(j & 255);
    v = (k < 128) ? Wr2[n * 128 + k] : -Wi2[n * 128 + k - 128];
  } else {
    const long j = i - 2916352; const int n = (int)(j >> 8), k = (int)(j & 255);
    v = (k < 128) ? Wi2[n * 128 + k] : Wr2[n * 128 + k - 128];
  }
  wws[i] = f2b(v);
}

// ---------------------------------------------------------------------------
extern "C" void kernel_launch(void* const* d_in, const int* in_sizes, int n_in,
                              void* d_out, int out_size, void* d_ws,
                              size_t ws_size, hipStream_t stream) {
  (void)in_sizes; (void)n_in; (void)out_size;
  const float* x   = (const float*)d_in[0];
  const float* Wd1 = (const float*)d_in[1];
  const float* bd1 = (const float*)d_in[2];
  const float* Wd2 = (const float*)d_in[3];
  const float* bd2 = (const float*)d_in[4];
  const float* Wq  = (const float*)d_in[5];
  const float* bq  = (const float*)d_in[6];
  const float* Wk  = (const float*)d_in[7];
  const float* bk  = (const float*)d_in[8];
  const float* Wv  = (const float*)d_in[9];
  const float* bv  = (const float*)d_in[10];
  const float* Wu1 = (const float*)d_in[11];
  const float* bu1 = (const float*)d_in[12];
  const float* Wu2 = (const float*)d_in[13];
  const float* bu2 = (const float*)d_in[14];
  const float* gamma = (const float*)d_in[15];
  const float* beta  = (const float*)d_in[16];
  const float* Wr1 = (const float*)d_in[17];
  const float* br1 = (const float*)d_in[18];
  const float* Wr2 = (const float*)d_in[19];
  const float* br2 = (const float*)d_in[20];
  const float* Wi1 = (const float*)d_in[21];
  const float* bi1 = (const float*)d_in[22];
  const float* Wi2 = (const float*)d_in[23];
  const float* bi2 = (const float*)d_in[24];
  float* out = (float*)d_out;

  // ---- workspace carve-up ----
  float* bws = (float*)d_ws;                   // 1024 f32
  ushort* wws = (ushort*)(bws + 1024);         // 2949120 ushort
  const size_t kFixed = 1024 * 4 + 2949120 * 2;   // 5902336 B
  const size_t kPerBatch = 90177536;              // bytes (see buffer list)
  int CB = 1;
  const int cands[5] = {16, 8, 4, 2, 1};
  for (int ci = 0; ci < 5; ++ci)
    if (kFixed + (size_t)cands[ci] * kPerBatch <= ws_size) { CB = cands[ci]; break; }

  char* base = (char*)d_ws + kFixed;
  const long R = (long)CB * N_;            // conv rows per chunk
  const long Fr = (long)CB * 7 * N_;       // fft rows per chunk
  ushort* xt  = (ushort*)base;             // CB*3145728
  ushort* y1  = xt  + CB * 3145728L;       // R*128
  ushort* y   = y1  + R * 128;             // R*128
  ushort* qkb = y   + R * 128;             // R*256
  ushort* vT  = qkb + R * 256;             // 128*R
  ushort* P   = vT  + R * 128;             // CB*2048*2048
  ushort* o   = P   + (long)CB * N_ * N_;  // R*128
  ushort* u1  = o   + R * 128;             // R*1536
  ushort* re  = u1  + R * 1536;            // Fr*128
  ushort* im  = re  + Fr * 128;            // Fr*128
  ushort* G   = im  + Fr * 128;            // Fr*512 (unused now; kept for layout)
  float*  S   = (float*)(G + Fr * 512);    // CB*2048*2048
  float*  hn  = S   + (long)CB * N_ * N_;  // R*1536
  float*  hr  = hn  + R * 1536;            // Fr*128
  float*  hi  = hr  + Fr * 128;            // Fr*128

  const dim3 blk(256);
  const float scale = 0.125f;              // 1/sqrt(D/2)

  // weight prep (once per call; ~6 MB)
  prep_k<<<dim3(11520), blk, 0, stream>>>(Wd1, Wd2, Wq, Wk, Wv, Wu1, Wu2,
                                          Wr1, Wr2, Wi1, Wi2, bq, bk, br1,
                                          bi1, br2, bi2, wws, bws);
  ushort* Wd1b = wws;
  ushort* Wd2b = wws + 196608;
  ushort* Wqkb = wws + 212992;
  ushort* Wvb  = wws + 245760;
  ushort* Wu1b = wws + 262144;
  ushort* Wu2b = wws + 458752;
  ushort* W13b = wws + 2818048;            // [Wr1|Wi1] rows: Wr1b=W13b, Wi1b=W13b+16384
  ushort* Whrb = wws + 2883584;
  ushort* Whib = wws + 2916352;
  float* bqk = bws;
  float* bhr = bws + 768;
  float* bhi = bws + 896;

  for (int c = 0; c < 16 / CB; ++c) {
    const int b0 = c * CB;
    const float* xc = x + (long)b0 * TND_;
    float* oc = out + (long)b0 * TND_;
    const int GY = CB * 16;     // R/128
    const int GF = CB * 112;    // Fr/128

    // x -> xt (bf16 transposed view)
    xt_k<<<dim3(CB * 12288), blk, 0, stream>>>(xc, xt);
    // conv_down: y1 = relu(xt@Wd1^T+bd1); y = y1@Wd2^T+bd2
    mgemm<1, 1><<<dim3(1, GY), blk, 0, stream>>>(
        xt, Wd1b, bd1, y1, 1536, 1536, 1536, 128, 1.f, 0, 0, 0, 0, 0);
    mgemm<0, 1><<<dim3(1, GY), blk, 0, stream>>>(
        y1, Wd2b, bd2, y, 128, 128, 128, 128, 1.f, 0, 0, 0, 0, 0);
    // [q|k] and v^T
    mgemm<0, 1><<<dim3(2, GY), blk, 0, stream>>>(
        y, Wqkb, bqk, qkb, 128, 128, 128, 256, 1.f, 0, 0, 0, 0, 0);
    mgemm<0, 2><<<dim3(1, GY), blk, 0, stream>>>(
        y, Wvb, bv, vT, 128, 128, 128, (int)R, 1.f, 0, 0, 0, 0, 0);
    // logits S = 0.125 * q@k^T (fp32)
    mgemm<0, 0><<<dim3(16, 16, CB), blk, 0, stream>>>(
        qkb, qkb + 128, nullptr, S, 128, 256, 256, 2048, scale,
        524288, 524288, 4194304, 0, 0);
    softmax_k<<<dim3(N_, CB), blk, 0, stream>>>(S, P);
    // o = P @ v  (B = vT as W[N=128][K=2048])
    mgemm<0, 1><<<dim3(1, 16, CB), blk, 0, stream>>>(
        P, vT, nullptr, o, 2048, 2048, (int)R, 128, 1.f,
        4194304, 2048, 262144, 0, 0);
    // conv_up: u1 = relu(o@Wu1^T+bu1); GEMM2+residual+LN -> hn
    mgemm<1, 1><<<dim3(12, GY), blk, 0, stream>>>(
        o, Wu1b, bu1, u1, 128, 128, 128, 1536, 1.f, 0, 0, 0, 0, 0);
    mgemm_ln<<<dim3(12, GY), blk, 0, stream>>>(u1, Wu2b, bu2, xc, gamma, beta, hn);
    // rfft
    rfft_k<<<dim3(CB * 1024), blk, 0, stream>>>(hn, re, im);
    // fused FFT dual-path MLP -> hr, hi (fp32)
    fft_mlp_k<<<dim3(GF), blk, 0, stream>>>(
        re, im, W13b, W13b + 16384, br1, bi1, Whrb, Whib, bhr, bhi, hr, hi);
    // irfft + residual
    irfft_k<<<dim3(CB * 1024), blk, 0, stream>>>(hr, hi, xc, oc);
  }
}

// Round 3
// 1785.439 us; speedup vs baseline: 1.1932x; 1.1932x over previous
//
#include <hip/hip_runtime.h>
#include <math.h>

#define T_ 12
#define N_ 2048
#define D_ 128
#define ND_ 262144            // N_*D_ = 2^18
#define TND_ 3145728L         // T_*ND_

typedef __attribute__((ext_vector_type(8))) short short8;   // 8 bf16 (4 VGPRs)
typedef __attribute__((ext_vector_type(4))) float f32x4;
typedef union { float4 v; float a[4]; } f4u;

__device__ __forceinline__ ushort f2b(float f) {            // fp32 -> bf16 RNE
  unsigned u = __float_as_uint(f);
  u += 0x7fffu + ((u >> 16) & 1u);
  return (ushort)(u >> 16);
}
__device__ __forceinline__ float b2f(ushort s) {
  return __uint_as_float(((unsigned)s) << 16);
}

// Direct global->LDS DMA, 16B per lane. LDS dest is wave-uniform base;
// HW writes lane l's 16B at base + l*16 (m97/m104). Matches our fragment
// layout As + blk*512 + l*8 (ushort) exactly.
__device__ __forceinline__ void gload16(const ushort* g, ushort* lds) {
  __builtin_amdgcn_global_load_lds(
      (const __attribute__((address_space(1))) void*)g,
      (__attribute__((address_space(3))) void*)lds, 16, 0, 0);
}

// cos/sin(2*pi*k/12); cos(2*pi*f*t/12) == COS12[(f*t)%12]
__constant__ float COS12[12] = {
    1.0f, 0.8660254037844387f, 0.5f, 0.0f, -0.5f, -0.8660254037844387f,
    -1.0f, -0.8660254037844387f, -0.5f, 0.0f, 0.5f, 0.8660254037844387f};
__constant__ float SIN12[12] = {
    0.0f, 0.5f, 0.8660254037844387f, 1.0f, 0.8660254037844387f, 0.5f,
    0.0f, -0.5f, -0.8660254037844387f, -1.0f, -0.8660254037844387f, -0.5f};

// ---------------------------------------------------------------------------
// bf16 MFMA GEMM: C[M,N] = ACT( alpha * A@B^T + bias ), A bf16 [M,K] (lda),
// B bf16 [N,K] (ldb, torch Linear weight layout). Tile 128x128, BK=32,
// 4 waves, each wave 32(M)x128(N) = 2x8 MFMAs of 16x16x32.
// LDS tiles in MFMA-fragment order via global_load_lds (wave-uniform base +
// lane*16B): block ri holds rows ri*16+(l&15), k (l>>4)*8..+7 at
// offset ri*512 + l*8. Lane-contiguous 16B => conflict-free (m136).
// ACT: 0 none, 1 relu, 2 gelu(exact). OUT: 0 f32, 1 bf16, 2 bf16 transposed
// (C^T, for vT). off0/off1: epilogue col remap c += (c<128 ? off0 : off1).
// Requires M%128==0, N%128==0, K%32==0.
// ---------------------------------------------------------------------------
template <int ACT, int OUT>
__global__ __launch_bounds__(256) void mgemm(
    const ushort* __restrict__ A, const ushort* __restrict__ B,
    const float* __restrict__ bias, void* __restrict__ Cv,
    int K, int lda, int ldb, int ldc, float alpha,
    long sAb, long sBb, long sCb, int off0, int off1) {
  __shared__ ushort As[4096];
  __shared__ ushort Bs[4096];
  const int tid = threadIdx.x;
  const int w = tid >> 6;
  const int l = tid & 63;
  const int lr = l & 15;        // fragment row/col within 16
  const int lg = l >> 4;        // k-group (0..3)
  const int row0 = blockIdx.y * 128;
  const int col0 = blockIdx.x * 128;
  const ushort* Ap = A + sAb * blockIdx.z;
  const ushort* Bp = B + sBb * blockIdx.z;

  f32x4 acc[2][8];
#pragma unroll
  for (int i = 0; i < 2; ++i)
#pragma unroll
    for (int j = 0; j < 8; ++j) acc[i][j] = (f32x4){0.f, 0.f, 0.f, 0.f};

  const int ba = w, bb2 = w + 4;   // each wave stages 2 A-blocks + 2 B-blocks
  const ushort* Apl = Ap + (long)(row0 + ba * 16 + lr) * lda + lg * 8;
  const ushort* Apl2 = Ap + (long)(row0 + bb2 * 16 + lr) * lda + lg * 8;
  const ushort* Bpl = Bp + (long)(col0 + ba * 16 + lr) * ldb + lg * 8;
  const ushort* Bpl2 = Bp + (long)(col0 + bb2 * 16 + lr) * ldb + lg * 8;
  for (int k0 = 0; k0 < K; k0 += 32) {
    gload16(Apl + k0, As + ba * 512);
    gload16(Apl2 + k0, As + bb2 * 512);
    gload16(Bpl + k0, Bs + ba * 512);
    gload16(Bpl2 + k0, Bs + bb2 * 512);
    __syncthreads();
    const short8 a0 = *(const short8*)(As + (w * 2 + 0) * 512 + l * 8);
    const short8 a1 = *(const short8*)(As + (w * 2 + 1) * 512 + l * 8);
#pragma unroll
    for (int ni = 0; ni < 8; ++ni) {
      const short8 bfr = *(const short8*)(Bs + ni * 512 + l * 8);
      acc[0][ni] = __builtin_amdgcn_mfma_f32_16x16x32_bf16(a0, bfr, acc[0][ni], 0, 0, 0);
      acc[1][ni] = __builtin_amdgcn_mfma_f32_16x16x32_bf16(a1, bfr, acc[1][ni], 0, 0, 0);
    }
    __syncthreads();
  }

  // epilogue: C/D layout col=l&15, row=(l>>4)*4+reg  [m89/m91]
  const long Cz = sCb * blockIdx.z;
#pragma unroll
  for (int mi = 0; mi < 2; ++mi) {
    const int grow0 = row0 + w * 32 + mi * 16 + lg * 4;
    if (OUT == 2) {
      ushort* C = (ushort*)Cv;
#pragma unroll
      for (int ni = 0; ni < 8; ++ni) {
        const int c = col0 + ni * 16 + lr;
        const float bv = bias ? bias[c] : 0.f;
        ushort4 pk;
        float v0 = acc[mi][ni][0] * alpha + bv;
        float v1 = acc[mi][ni][1] * alpha + bv;
        float v2 = acc[mi][ni][2] * alpha + bv;
        float v3 = acc[mi][ni][3] * alpha + bv;
        if (ACT == 1) { v0 = fmaxf(v0, 0.f); v1 = fmaxf(v1, 0.f); v2 = fmaxf(v2, 0.f); v3 = fmaxf(v3, 0.f); }
        pk.x = f2b(v0); pk.y = f2b(v1); pk.z = f2b(v2); pk.w = f2b(v3);
        *(ushort4*)(C + (long)c * ldc + grow0) = pk;
      }
    } else {
#pragma unroll
      for (int ni = 0; ni < 8; ++ni) {
        const int c = col0 + ni * 16 + lr;
        const float bv = bias ? bias[c] : 0.f;
        const int cm = c + (c < 128 ? off0 : off1);
#pragma unroll
        for (int r = 0; r < 4; ++r) {
          float v = acc[mi][ni][r] * alpha + bv;
          if (ACT == 1) v = fmaxf(v, 0.f);
          if (ACT == 2) v = 0.5f * v * (1.0f + erff(v * 0.7071067811865475f));
          const long off = Cz + (long)(grow0 + r) * ldc + cm;
          if (OUT == 0) ((float*)Cv)[off] = v;
          else ((ushort*)Cv)[off] = f2b(v);
        }
      }
    }
  }
}

// ---------------------------------------------------------------------------
// conv_up GEMM2 fused with bias + residual(x fp32) + LayerNorm -> hn fp32.
// ---------------------------------------------------------------------------
__global__ __launch_bounds__(256) void mgemm_ln(
    const ushort* __restrict__ A, const ushort* __restrict__ B,
    const float* __restrict__ bias, const float* __restrict__ x,
    const float* __restrict__ gamma, const float* __restrict__ beta,
    float* __restrict__ hn) {
  const int K = 1536;
  __shared__ ushort As[4096];
  __shared__ ushort Bs[4096];
  const int tid = threadIdx.x;
  const int w = tid >> 6;
  const int l = tid & 63;
  const int lr = l & 15;
  const int lg = l >> 4;
  const int row0 = blockIdx.y * 128;
  const int t = blockIdx.x;
  const int col0 = t * 128;

  f32x4 acc[2][8];
#pragma unroll
  for (int i = 0; i < 2; ++i)
#pragma unroll
    for (int j = 0; j < 8; ++j) acc[i][j] = (f32x4){0.f, 0.f, 0.f, 0.f};

  const int ba = w, bb2 = w + 4;
  const ushort* Apl = A + (long)(row0 + ba * 16 + lr) * K + lg * 8;
  const ushort* Apl2 = A + (long)(row0 + bb2 * 16 + lr) * K + lg * 8;
  const ushort* Bpl = B + (long)(col0 + ba * 16 + lr) * K + lg * 8;
  const ushort* Bpl2 = B + (long)(col0 + bb2 * 16 + lr) * K + lg * 8;
  for (int k0 = 0; k0 < K; k0 += 32) {
    gload16(Apl + k0, As + ba * 512);
    gload16(Apl2 + k0, As + bb2 * 512);
    gload16(Bpl + k0, Bs + ba * 512);
    gload16(Bpl2 + k0, Bs + bb2 * 512);
    __syncthreads();
    const short8 a0 = *(const short8*)(As + (w * 2 + 0) * 512 + l * 8);
    const short8 a1 = *(const short8*)(As + (w * 2 + 1) * 512 + l * 8);
#pragma unroll
    for (int ni = 0; ni < 8; ++ni) {
      const short8 bfr = *(const short8*)(Bs + ni * 512 + l * 8);
      acc[0][ni] = __builtin_amdgcn_mfma_f32_16x16x32_bf16(a0, bfr, acc[0][ni], 0, 0, 0);
      acc[1][ni] = __builtin_amdgcn_mfma_f32_16x16x32_bf16(a1, bfr, acc[1][ni], 0, 0, 0);
    }
    __syncthreads();
  }

#pragma unroll
  for (int mi = 0; mi < 2; ++mi) {
#pragma unroll
    for (int r = 0; r < 4; ++r) {
      const int gr = row0 + w * 32 + mi * 16 + lg * 4 + r;
      const int bb = gr >> 11;
      const int nn = gr & 2047;
      const long base = ((long)(bb * 12 + t) << 18) + (long)nn * 128;
      float h[8];
      float s1 = 0.f, s2 = 0.f;
#pragma unroll
      for (int ni = 0; ni < 8; ++ni) {
        const int d = ni * 16 + lr;
        const float v = acc[mi][ni][r] + bias[col0 + d] + x[base + d];
        h[ni] = v;
        s1 += v;
        s2 += v * v;
      }
#pragma unroll
      for (int m = 1; m < 16; m <<= 1) {
        s1 += __shfl_xor(s1, m);
        s2 += __shfl_xor(s2, m);
      }
      const float mu = s1 * (1.f / 128.f);
      const float rstd = rsqrtf(s2 * (1.f / 128.f) - mu * mu + 1e-5f);
#pragma unroll
      for (int ni = 0; ni < 8; ++ni) {
        const int d = ni * 16 + lr;
        hn[base + d] = (h[ni] - mu) * rstd * gamma[d] + beta[d];
      }
    }
  }
}

// ---------------------------------------------------------------------------
// Row softmax over 2048 fp32 logits -> bf16 probabilities.
// grid = (2048, CB), block = 256 (4 waves). Vectorized 8 elems/thread;
// wave shuffle-reduce + 2 barriers (vs 16-barrier tree).
// ---------------------------------------------------------------------------
__global__ __launch_bounds__(256) void softmax_k(const float* __restrict__ S,
                                                 ushort* __restrict__ P) {
  const long row = ((long)blockIdx.y * N_ + blockIdx.x) * N_;
  const int tid = threadIdx.x;
  const int w = tid >> 6;
  f4u va, vb;
  va.v = *(const float4*)(S + row + tid * 8);
  vb.v = *(const float4*)(S + row + tid * 8 + 4);
  float v[8];
#pragma unroll
  for (int j = 0; j < 4; ++j) { v[j] = va.a[j]; v[j + 4] = vb.a[j]; }
  float mx = v[0];
#pragma unroll
  for (int j = 1; j < 8; ++j) mx = fmaxf(mx, v[j]);
#pragma unroll
  for (int m = 1; m < 64; m <<= 1) mx = fmaxf(mx, __shfl_xor(mx, m));
  __shared__ float redm[4], reds[4];
  if ((tid & 63) == 0) redm[w] = mx;
  __syncthreads();
  mx = fmaxf(fmaxf(redm[0], redm[1]), fmaxf(redm[2], redm[3]));
  float sum = 0.0f;
#pragma unroll
  for (int j = 0; j < 8; ++j) {
    v[j] = expf(v[j] - mx);
    sum += v[j];
  }
#pragma unroll
  for (int m = 1; m < 64; m <<= 1) sum += __shfl_xor(sum, m);
  if ((tid & 63) == 0) reds[w] = sum;
  __syncthreads();
  const float inv = 1.0f / (reds[0] + reds[1] + reds[2] + reds[3]);
  short8 o;
#pragma unroll
  for (int j = 0; j < 8; ++j) o[j] = (short)f2b(v[j] * inv);
  *(short8*)(P + row + tid * 8) = o;
}

// rfft over T=12: hn fp32 [CB,12,2048,128] -> re/im bf16 [CB,7,2048,128]
// 4 elems (contiguous d) per thread, float4 loads / ushort4 stores.
__global__ __launch_bounds__(256) void rfft_k(const float* __restrict__ hn,
                                              ushort* __restrict__ re,
                                              ushort* __restrict__ im) {
  const long i = (long)blockIdx.x * 256 + threadIdx.x;   // grid = CB*256
  const int bb = (int)(i >> 16);
  const int nd = (int)(i & 65535) * 4;
  f4u ht[12];
#pragma unroll
  for (int t = 0; t < 12; ++t)
    ht[t].v = *(const float4*)(hn + ((long)(bb * T_ + t) << 18) + nd);
#pragma unroll
  for (int f = 0; f < 7; ++f) {
    float sr[4] = {0.f, 0.f, 0.f, 0.f}, si[4] = {0.f, 0.f, 0.f, 0.f};
#pragma unroll
    for (int t = 0; t < 12; ++t) {
      const int k = (f * t) % 12;
      const float ck = COS12[k], sk = SIN12[k];
#pragma unroll
      for (int c = 0; c < 4; ++c) {
        sr[c] = fmaf(ht[t].a[c], ck, sr[c]);
        si[c] = fmaf(ht[t].a[c], sk, si[c]);
      }
    }
    const long off = ((long)(bb * 7 + f) << 18) + nd;
    ushort4 pr, pi;
    pr.x = f2b(sr[0]); pr.y = f2b(sr[1]); pr.z = f2b(sr[2]); pr.w = f2b(sr[3]);
    pi.x = f2b(-si[0]); pi.y = f2b(-si[1]); pi.z = f2b(-si[2]); pi.w = f2b(-si[3]);
    *(ushort4*)(re + off) = pr;
    *(ushort4*)(im + off) = pi;
  }
}

// irfft (n=12, numpy C2R: imag of DC/Nyquist dropped) + residual -> fp32 out
// 4 elems per thread, float4 loads/stores.
__global__ __launch_bounds__(256) void irfft_k(const float* __restrict__ hr,
                                               const float* __restrict__ hi,
                                               const float* __restrict__ x,
                                               float* __restrict__ out) {
  const long i = (long)blockIdx.x * 256 + threadIdx.x;   // grid = CB*256
  const int bb = (int)(i >> 16);
  const int nd = (int)(i & 65535) * 4;
  f4u r[7], m[7];
#pragma unroll
  for (int f = 0; f < 7; ++f) {
    const long off = ((long)(bb * 7 + f) << 18) + nd;
    r[f].v = *(const float4*)(hr + off);
    m[f].v = *(const float4*)(hi + off);
  }
#pragma unroll
  for (int t = 0; t < 12; ++t) {
    const long xi = ((long)(bb * T_ + t) << 18) + nd;
    f4u xv;
    xv.v = *(const float4*)(x + xi);
    f4u s;
#pragma unroll
    for (int c = 0; c < 4; ++c)
      s.a[c] = r[0].a[c] + ((t & 1) ? -r[6].a[c] : r[6].a[c]);
#pragma unroll
    for (int f = 1; f < 6; ++f) {
      const int k = (f * t) % 12;
      const float ck = 2.0f * COS12[k], sk = 2.0f * SIN12[k];
#pragma unroll
      for (int c = 0; c < 4; ++c)
        s.a[c] += r[f].a[c] * ck - m[f].a[c] * sk;
    }
#pragma unroll
    for (int c = 0; c < 4; ++c) s.a[c] = s.a[c] * (1.0f / 12.0f) + xv.a[c];
    *(float4*)(out + xi) = s.v;
  }
}

// x fp32 [CB,12,2048,128] -> xt bf16 [CB*2048, 1536] (transposed conv_down in)
// 8 consecutive d per thread: 2x float4 read + 16B short8 write.
__global__ __launch_bounds__(256) void xt_k(const float* __restrict__ x,
                                            ushort* __restrict__ xt) {
  const long i = (long)blockIdx.x * 256 + threadIdx.x;   // grid = CB*1536
  const int d8 = (int)(i & 15) * 8;
  const long rr = i >> 4;
  const int nn = (int)(rr & 2047);
  const long r2 = rr >> 11;
  const int t = (int)(r2 % 12);
  const int bb = (int)(r2 / 12);
  f4u a, b;
  a.v = *(const float4*)(x + i * 8);
  b.v = *(const float4*)(x + i * 8 + 4);
  short8 o;
#pragma unroll
  for (int j = 0; j < 4; ++j) {
    o[j] = (short)f2b(a.a[j]);
    o[j + 4] = (short)f2b(b.a[j]);
  }
  *(short8*)(xt + ((long)bb * 2048 + nn) * 1536 + t * 128 + d8) = o;
}

// ---------------------------------------------------------------------------
// Weight prep: fp32 -> bf16 with concat/sign-fold fusions + bias combos.
// Weight region (ushort elems):
//   Wd1b@0(196608) Wd2b@196608(16384) Wqkb@212992(32768=[Wq|Wk])
//   Wvb@245760(16384) Wu1b@262144(196608) Wu2b@458752(2359296)
//   W13b@2818048(32768=[Wr1|Wi1]) W24b@2850816(32768=[Wi1|Wr1])
//   Whrb@2883584(32768: [n][k]: k<128?Wr2:-Wi2)  Whib@2916352(32768: Wi2|Wr2)
// Bias region (f32): bqk@0(256) b13@256(256) b24@512(256) bhr@768(128) bhi@896(128)
// ---------------------------------------------------------------------------
__global__ __launch_bounds__(256) void prep_k(
    const float* Wd1, const float* Wd2, const float* Wq, const float* Wk,
    const float* Wv, const float* Wu1, const float* Wu2, const float* Wr1,
    const float* Wr2, const float* Wi1, const float* Wi2,
    const float* bq, const float* bk, const float* br1, const float* bi1,
    const float* br2, const float* bi2,
    ushort* __restrict__ wws, float* __restrict__ bws) {
  const long i = (long)blockIdx.x * 256 + threadIdx.x;
  if (i < 256) bws[i] = (i < 128) ? bq[i] : bk[i - 128];
  else if (i < 512) { const int j = i - 256; bws[i] = (j < 128) ? br1[j] : bi1[j - 128]; }
  else if (i < 768) { const int j = i - 512; bws[i] = (j < 128) ? bi1[j] : br1[j - 128]; }
  else if (i < 896) { const int j = i - 768; bws[i] = br2[j] - bi2[j]; }
  else if (i < 1024) { const int j = i - 896; bws[i] = bi2[j] + br2[j]; }
  if (i >= 2949120) return;
  float v;
  if (i < 196608) v = Wd1[i];
  else if (i < 212992) v = Wd2[i - 196608];
  else if (i < 245760) { const long j = i - 212992; v = (j < 16384) ? Wq[j] : Wk[j - 16384]; }
  else if (i < 262144) v = Wv[i - 245760];
  else if (i < 458752) v = Wu1[i - 262144];
  else if (i < 2818048) v = Wu2[i - 458752];
  else if (i < 2850816) { const long j = i - 2818048; v = (j < 16384) ? Wr1[j] : Wi1[j - 16384]; }
  else if (i < 2883584) { const long j = i - 2850816; v = (j < 16384) ? Wi1[j] : Wr1[j - 16384]; }
  else if (i < 2916352) {
    const long j = i - 2883584; const int n = (int)(j >> 8), k = (int)(j & 255);
    v = (k < 128) ? Wr2[n * 128 + k] : -Wi2[n * 128 + k - 128];
  } else {
    const long j = i - 2916352; const int n = (int)(j >> 8), k = (int)(j & 255);
    v = (k < 128) ? Wi2[n * 128 + k] : Wr2[n * 128 + k - 128];
  }
  wws[i] = f2b(v);
}

// ---------------------------------------------------------------------------
extern "C" void kernel_launch(void* const* d_in, const int* in_sizes, int n_in,
                              void* d_out, int out_size, void* d_ws,
                              size_t ws_size, hipStream_t stream) {
  (void)in_sizes; (void)n_in; (void)out_size;
  const float* x   = (const float*)d_in[0];
  const float* Wd1 = (const float*)d_in[1];
  const float* bd1 = (const float*)d_in[2];
  const float* Wd2 = (const float*)d_in[3];
  const float* bd2 = (const float*)d_in[4];
  const float* Wq  = (const float*)d_in[5];
  const float* bq  = (const float*)d_in[6];
  const float* Wk  = (const float*)d_in[7];
  const float* bk  = (const float*)d_in[8];
  const float* Wv  = (const float*)d_in[9];
  const float* bv  = (const float*)d_in[10];
  const float* Wu1 = (const float*)d_in[11];
  const float* bu1 = (const float*)d_in[12];
  const float* Wu2 = (const float*)d_in[13];
  const float* bu2 = (const float*)d_in[14];
  const float* gamma = (const float*)d_in[15];
  const float* beta  = (const float*)d_in[16];
  const float* Wr1 = (const float*)d_in[17];
  const float* br1 = (const float*)d_in[18];
  const float* Wr2 = (const float*)d_in[19];
  const float* br2 = (const float*)d_in[20];
  const float* Wi1 = (const float*)d_in[21];
  const float* bi1 = (const float*)d_in[22];
  const float* Wi2 = (const float*)d_in[23];
  const float* bi2 = (const float*)d_in[24];
  float* out = (float*)d_out;

  // ---- workspace carve-up ----
  float* bws = (float*)d_ws;                   // 1024 f32
  ushort* wws = (ushort*)(bws + 1024);         // 2949120 ushort
  const size_t kFixed = 1024 * 4 + 2949120 * 2;   // 5902336 B
  const size_t kPerBatch = 90177536;              // bytes (see buffer list)
  int CB = 1;
  const int cands[5] = {16, 8, 4, 2, 1};
  for (int ci = 0; ci < 5; ++ci)
    if (kFixed + (size_t)cands[ci] * kPerBatch <= ws_size) { CB = cands[ci]; break; }

  char* base = (char*)d_ws + kFixed;
  const long R = (long)CB * N_;            // conv rows per chunk
  const long Fr = (long)CB * 7 * N_;       // fft rows per chunk
  ushort* xt  = (ushort*)base;             // CB*3145728
  ushort* y1  = xt  + CB * 3145728L;       // R*128
  ushort* y   = y1  + R * 128;             // R*128
  ushort* qkb = y   + R * 128;             // R*256
  ushort* vT  = qkb + R * 256;             // 128*R
  ushort* P   = vT  + R * 128;             // CB*2048*2048
  ushort* o   = P   + (long)CB * N_ * N_;  // R*128
  ushort* u1  = o   + R * 128;             // R*1536
  ushort* re  = u1  + R * 1536;            // Fr*128
  ushort* im  = re  + Fr * 128;            // Fr*128
  ushort* G   = im  + Fr * 128;            // Fr*512
  float*  S   = (float*)(G + Fr * 512);    // CB*2048*2048
  float*  hn  = S   + (long)CB * N_ * N_;  // R*1536
  float*  hr  = hn  + R * 1536;            // Fr*128
  float*  hi  = hr  + Fr * 128;            // Fr*128

  const dim3 blk(256);
  const float scale = 0.125f;              // 1/sqrt(D/2)

  // weight prep (once per call; ~6 MB)
  prep_k<<<dim3(11520), blk, 0, stream>>>(Wd1, Wd2, Wq, Wk, Wv, Wu1, Wu2,
                                          Wr1, Wr2, Wi1, Wi2, bq, bk, br1,
                                          bi1, br2, bi2, wws, bws);
  ushort* Wd1b = wws;
  ushort* Wd2b = wws + 196608;
  ushort* Wqkb = wws + 212992;
  ushort* Wvb  = wws + 245760;
  ushort* Wu1b = wws + 262144;
  ushort* Wu2b = wws + 458752;
  ushort* W13b = wws + 2818048;
  ushort* W24b = wws + 2850816;
  ushort* Whrb = wws + 2883584;
  ushort* Whib = wws + 2916352;
  float* bqk = bws;
  float* b13 = bws + 256;
  float* b24 = bws + 512;
  float* bhr = bws + 768;
  float* bhi = bws + 896;

  for (int c = 0; c < 16 / CB; ++c) {
    const int b0 = c * CB;
    const float* xc = x + (long)b0 * TND_;
    float* oc = out + (long)b0 * TND_;
    const int GY = CB * 16;     // R/128
    const int GF = CB * 112;    // Fr/128

    // x -> xt (bf16 transposed view)
    xt_k<<<dim3(CB * 1536), blk, 0, stream>>>(xc, xt);
    // conv_down: y1 = relu(xt@Wd1^T+bd1); y = y1@Wd2^T+bd2
    mgemm<1, 1><<<dim3(1, GY), blk, 0, stream>>>(
        xt, Wd1b, bd1, y1, 1536, 1536, 1536, 128, 1.f, 0, 0, 0, 0, 0);
    mgemm<0, 1><<<dim3(1, GY), blk, 0, stream>>>(
        y1, Wd2b, bd2, y, 128, 128, 128, 128, 1.f, 0, 0, 0, 0, 0);
    // [q|k] and v^T
    mgemm<0, 1><<<dim3(2, GY), blk, 0, stream>>>(
        y, Wqkb, bqk, qkb, 128, 128, 128, 256, 1.f, 0, 0, 0, 0, 0);
    mgemm<0, 2><<<dim3(1, GY), blk, 0, stream>>>(
        y, Wvb, bv, vT, 128, 128, 128, (int)R, 1.f, 0, 0, 0, 0, 0);
    // logits S = 0.125 * q@k^T (fp32)
    mgemm<0, 0><<<dim3(16, 16, CB), blk, 0, stream>>>(
        qkb, qkb + 128, nullptr, S, 128, 256, 256, 2048, scale,
        524288, 524288, 4194304, 0, 0);
    softmax_k<<<dim3(N_, CB), blk, 0, stream>>>(S, P);
    // o = P @ v  (B = vT as W[N=128][K=2048])
    mgemm<0, 1><<<dim3(1, 16, CB), blk, 0, stream>>>(
        P, vT, nullptr, o, 2048, 2048, (int)R, 128, 1.f,
        4194304, 2048, 262144, 0, 0);
    // conv_up: u1 = relu(o@Wu1^T+bu1); GEMM2+residual+LN -> hn
    mgemm<1, 1><<<dim3(12, GY), blk, 0, stream>>>(
        o, Wu1b, bu1, u1, 128, 128, 128, 1536, 1.f, 0, 0, 0, 0, 0);
    mgemm_ln<<<dim3(12, GY), blk, 0, stream>>>(u1, Wu2b, bu2, xc, gamma, beta, hn);
    // rfft
    rfft_k<<<dim3(CB * 256), blk, 0, stream>>>(hn, re, im);
    // FFT MLP layer 1 (concat): re -> [g1|g3], im -> [g2|g4] in G[M][512]
    mgemm<2, 1><<<dim3(2, GF), blk, 0, stream>>>(
        re, W13b, b13, G, 128, 128, 128, 512, 1.f, 0, 0, 0, 0, 128);
    mgemm<2, 1><<<dim3(2, GF), blk, 0, stream>>>(
        im, W24b, b24, G, 128, 128, 128, 512, 1.f, 0, 0, 0, 128, 256);
    // FFT MLP layer 2 (K=256 concat, sign-folded): hr, hi fp32
    mgemm<0, 0><<<dim3(1, GF), blk, 0, stream>>>(
        G, Whrb, bhr, hr, 256, 512, 256, 128, 1.f, 0, 0, 0, 0, 0);
    mgemm<0, 0><<<dim3(1, GF), blk, 0, stream>>>(
        G + 256, Whib, bhi, hi, 256, 512, 256, 128, 1.f, 0, 0, 0, 0, 0);
    // irfft + residual
    irfft_k<<<dim3(CB * 256), blk, 0, stream>>>(hr, hi, xc, oc);
  }
}